// Round 4
// baseline (465.761 us; speedup 1.0000x reference)
//
#include <hip/hip_runtime.h>
#include <math.h>

typedef unsigned short u16;
typedef unsigned int u32;
typedef __attribute__((ext_vector_type(8))) short bf16x8;
typedef __attribute__((ext_vector_type(4))) float f32x4;

#define S_LEN 2048
#define HID 4096
#define NH 32
#define NKV 8
#define HD 128
#define QS 6144  // fused qkv row stride (4096 Q | 1024 K | 1024 V)

__device__ __forceinline__ u16 f2bf(float f) {
  u32 u = __float_as_uint(f);
  u32 r = (u + 0x7FFFu + ((u >> 16) & 1u)) >> 16;
  return (u16)r;
}
__device__ __forceinline__ float bf2f(u16 v) {
  return __uint_as_float(((u32)v) << 16);
}
__device__ __forceinline__ f32x4 mfma16(bf16x8 a, bf16x8 b, f32x4 c) {
  return __builtin_amdgcn_mfma_f32_16x16x32_bf16(a, b, c, 0, 0, 0);
}
// async global->LDS, 16B per lane. LDS dest is wave-uniform base + lane*16.
__device__ __forceinline__ void async16(const u16* g, u16* l) {
  __builtin_amdgcn_global_load_lds(
      (__attribute__((address_space(1))) void*)g,
      (__attribute__((address_space(3))) void*)l, 16, 0, 0);
}
#if __has_builtin(__builtin_amdgcn_exp2f)
#define EXP2(x) __builtin_amdgcn_exp2f(x)
#else
#define EXP2(x) exp2f(x)
#endif

#define VMC(n) asm volatile("s_waitcnt vmcnt(" #n ")" ::: "memory")
#define LGKM(n) asm volatile("s_waitcnt lgkmcnt(" #n ")" ::: "memory")
#define SB __builtin_amdgcn_sched_barrier(0)
#define BAR __builtin_amdgcn_s_barrier()
#define P1 __builtin_amdgcn_s_setprio(1)
#define P0 __builtin_amdgcn_s_setprio(0)

// ---------------- fp32 -> bf16, all five tensors in one launch ---------------
__global__ __launch_bounds__(256) void conv_all(
    const float* __restrict__ hs, const float* __restrict__ wq,
    const float* __restrict__ wk, const float* __restrict__ wv,
    const float* __restrict__ wo, u16* __restrict__ dhs, u16* __restrict__ dwq,
    u16* __restrict__ dwk, u16* __restrict__ dwv, u16* __restrict__ dwo) {
  int i = blockIdx.x * 256 + threadIdx.x;
  const float* src;
  u16* dst;
  int off;
  if (i < 2097152) { src = hs; dst = dhs; off = 0; }
  else if (i < 6291456) { src = wq; dst = dwq; off = 2097152; }
  else if (i < 7340032) { src = wk; dst = dwk; off = 6291456; }
  else if (i < 8388608) { src = wv; dst = dwv; off = 7340032; }
  else { src = wo; dst = dwo; off = 8388608; }
  int j = i - off;
  float4 v = ((const float4*)src)[j];
  ushort4 o;
  o.x = f2bf(v.x); o.y = f2bf(v.y); o.z = f2bf(v.z); o.w = f2bf(v.w);
  ((ushort4*)dst)[j] = o;
}

// ---------------- 256xBN 8-phase GEMM, one-phase-ahead ds pipeline -----------
// C[M,N] = A[M,K] * B[N,K]^T.  BM=256, BN=NJ*64 (192 or 128), BK=64,
// 512 thr = 8 waves (4M x 2N, wave tile 64 x BN/2).  LDS dynamic:
// As[2][256][64] | Bs[2][BN][64] bf16, chunk-XOR swizzled on BOTH the
// pre-swizzled global source of global_load_lds (linear LDS dest) and the
// ds_read_b128 side.  Each phase issues the NEXT phase's fragment ds_reads
// (after the entry barrier) and waits only lgkmcnt(n_issued_this_phase):
// in-order DS completion guarantees this phase's operands are done.
// Counted vmcnt(NJ) at phases 4/8 only; setprio around MFMA clusters.
// Grid = 8 * (N/BN)  (M == 2048 -> 8 M-tiles, exact multiple of 8 XCDs).

#define DSA(dst, qi, d)                                                    \
  {                                                                        \
    const u16* p_ = As + (d)*16384 + (wm * 64 + (qi)*32 + cl) * 64;        \
    _Pragma("unroll") for (int ii = 0; ii < 2; ii++)                       \
        _Pragma("unroll") for (int kk = 0; kk < 2; kk++)                   \
            dst[ii][kk] =                                                  \
        *(const bf16x8*)(p_ + ii * 1024 + ((c0 ^ (kk << 2)) << 3));        \
  }

#define DSB(dst, qj, d)                                                    \
  {                                                                        \
    const u16* p_ =                                                        \
        Bs + (d)*BSTR + (wn * (BN / 2) + (qj) * (BN / 4) + cl) * 64;       \
    _Pragma("unroll") for (int jj = 0; jj < NJ; jj++)                      \
        _Pragma("unroll") for (int kk = 0; kk < 2; kk++)                   \
            dst[jj][kk] =                                                  \
        *(const bf16x8*)(p_ + jj * 1024 + ((c0 ^ (kk << 2)) << 3));        \
  }

#define MM(qi, qj, asrc, bsrc)                                             \
  {                                                                        \
    _Pragma("unroll") for (int ii = 0; ii < 2; ii++)                       \
        _Pragma("unroll") for (int jj = 0; jj < NJ; jj++)                  \
            _Pragma("unroll") for (int kk = 0; kk < 2; kk++)               \
                acc[(qi)*2 + ii][(qj)*NJ + jj] =                           \
        mfma16(asrc[ii][kk], bsrc[jj][kk], acc[(qi)*2 + ii][(qj)*NJ + jj]);\
  }

#define LGKM_NB()                           \
  do {                                      \
    if constexpr (NJ == 3) LGKM(6);         \
    else LGKM(4);                           \
  } while (0)
#define LGKM_NB4()                          \
  do {                                      \
    if constexpr (NJ == 3) LGKM(10);        \
    else LGKM(8);                           \
  } while (0)
#define VMCNJ()                             \
  do {                                      \
    if constexpr (NJ == 3) VMC(3);          \
    else VMC(2);                            \
  } while (0)

template <int NJ>
__global__ __launch_bounds__(512, 2) void gemm8p(
    const u16* __restrict__ A, const u16* __restrict__ B,
    u16* __restrict__ Cb, float* __restrict__ Cf, int N, int K) {
  constexpr int BN = NJ * 64;
  constexpr int BSTR = BN * 64;  // u16 per B dbuf
  extern __shared__ u16 lds[];
  u16* As = lds;           // [2][256*64]
  u16* Bs = lds + 32768;   // [2][BN*64]
  const int tid = threadIdx.x;
  const int lane = tid & 63, wv = tid >> 6;
  const int cl = lane & 15, qd = lane >> 4;
  const int wm = wv >> 1, wn = wv & 1;  // 4M x 2N waves
  const int c0 = qd ^ (cl & 7);

  // XCD-aware block swizzle (grid %8==0), decode M-fast (M-tiles == 8)
  const int cpx = gridDim.x >> 3;
  const int swz = (blockIdx.x & 7) * cpx + (blockIdx.x >> 3);
  const int m0 = (swz & 7) * 256;
  const int n0 = (swz >> 3) * BN;

  // per-lane staged-load source offsets (u16 elements); lane covers LDS
  // (row r, slot s), fetches global chunk c = s ^ (r&7)
  u32 aof[4], bof[NJ];
#pragma unroll
  for (int q = 0; q < 4; q++) {
    int r = q * 64 + wv * 8 + (lane >> 3);
    int c = (lane & 7) ^ (r & 7);
    aof[q] = (u32)(m0 + r) * K + c * 8;
  }
#pragma unroll
  for (int q = 0; q < NJ; q++) {
    int r = q * 64 + wv * 8 + (lane >> 3);
    int c = (lane & 7) ^ (r & 7);
    bof[q] = (u32)(n0 + r) * K + c * 8;
  }
  const int sbo = wv * 512;  // wave-uniform LDS stage offset

  auto STA = [&](int tt, int d, int ra) {
    async16(A + (size_t)tt * 64 + aof[ra], As + d * 16384 + ra * 4096 + sbo);
  };
  auto STB = [&](int tt, int d, int rb) {
    async16(B + (size_t)tt * 64 + bof[rb], Bs + d * BSTR + rb * 4096 + sbo);
  };

  f32x4 acc[4][2 * NJ];
  f32x4 zz = {0.f, 0.f, 0.f, 0.f};
#pragma unroll
  for (int i = 0; i < 4; i++)
#pragma unroll
    for (int j = 0; j < 2 * NJ; j++) acc[i][j] = zz;
  bf16x8 A0r[2][2], A1r[2][2], B0r[NJ][2], B1r[NJ][2];

  const int NT = K >> 6;  // 64-wide K-tiles; NT even

  // prologue: A(0)+B(0) -> dbuf0, B(1) -> dbuf1; preload tile0 frag regs
  STA(0, 0, 0); STA(0, 0, 1); STA(0, 0, 2); STA(0, 0, 3);
  STB(0, 0, 0); STB(0, 0, 1);
  if constexpr (NJ == 3) STB(0, 0, 2);
  STB(1, 1, 0); STB(1, 1, 1);
  if constexpr (NJ == 3) STB(1, 1, 2);
  VMCNJ();  // A(0), B(0) landed; B(1) in flight
  SB;
  BAR;
  DSA(A0r, 0, 0); DSB(B0r, 0, 0);
  SB; LGKM(0); SB;

  for (int it = 0; it < (NT >> 1); ++it) {
    const int t = it * 2;          // tiles t (dbuf0), t+1 (dbuf1)
    const bool s2 = (t + 2) < NT;  // NT even => also guards t+3
    // ph1: MM(0,0) tile t | ds: B1(dbuf0) for ph2 | stage (t+1)A -> dbuf1
    STA(t + 1, 1, 0); STA(t + 1, 1, 1);
    BAR; DSB(B1r, 1, 0); SB; LGKM_NB(); SB;
    P1; MM(0, 0, A0r, B0r); P0; SB; BAR;
    // ph2: MM(0,1) | ds: A1(dbuf0) for ph3 | stage (t+1)A
    STA(t + 1, 1, 2); STA(t + 1, 1, 3);
    BAR; DSA(A1r, 1, 0); SB; LGKM(4); SB;
    P1; MM(0, 1, A0r, B1r); P0; SB; BAR;
    // ph3: MM(1,0) | no ds | stage (t+2)B -> dbuf0 (dbuf0-B reads done ph2)
    if (s2) { STB(t + 2, 0, 0); STB(t + 2, 0, 1); }
    BAR; SB; LGKM(0); SB;
    P1; MM(1, 0, A1r, B0r); P0; SB; BAR;
    // ph4: MM(1,1) | VMC: tile t+1 landed | ds: B0,A0(dbuf1) for ph5
    if (s2) {
      if constexpr (NJ == 3) STB(t + 2, 0, 2);
      VMCNJ();
    } else {
      VMC(0);
    }
    BAR; DSB(B0r, 0, 1); DSA(A0r, 0, 1); SB; LGKM_NB4(); SB;
    P1; MM(1, 1, A1r, B1r); P0; SB; BAR;
    // ph5: tile t+1 MM(0,0) | ds: B1(dbuf1) for ph6 | stage (t+2)A -> dbuf0
    if (s2) { STA(t + 2, 0, 0); STA(t + 2, 0, 1); }
    BAR; DSB(B1r, 1, 1); SB; LGKM_NB(); SB;
    P1; MM(0, 0, A0r, B0r); P0; SB; BAR;
    // ph6: MM(0,1) | ds: A1(dbuf1) for ph7 | stage (t+2)A
    if (s2) { STA(t + 2, 0, 2); STA(t + 2, 0, 3); }
    BAR; DSA(A1r, 1, 1); SB; LGKM(4); SB;
    P1; MM(0, 1, A0r, B1r); P0; SB; BAR;
    // ph7: MM(1,0) | no ds | stage (t+3)B -> dbuf1 (dbuf1-B reads done ph6)
    if (s2) { STB(t + 3, 1, 0); STB(t + 3, 1, 1); }
    BAR; SB; LGKM(0); SB;
    P1; MM(1, 0, A1r, B0r); P0; SB; BAR;
    // ph8: MM(1,1) | VMC: tile t+2 landed | ds: B0,A0(dbuf0) for next ph1
    if (s2) {
      if constexpr (NJ == 3) STB(t + 3, 1, 2);
      VMCNJ();
    } else {
      VMC(0);
    }
    BAR; DSB(B0r, 0, 0); DSA(A0r, 0, 0); SB; LGKM_NB4(); SB;
    P1; MM(1, 1, A1r, B1r); P0; SB; BAR;
  }

  // epilogue: C-write (C/D layout: col=lane&15, row=(lane>>4)*4+reg)
#pragma unroll
  for (int i = 0; i < 4; i++)
#pragma unroll
    for (int j = 0; j < 2 * NJ; j++) {
      int row = m0 + wm * 64 + i * 16 + qd * 4;
      int col = n0 + wn * (BN / 2) + (j / NJ) * (BN / 4) + (j % NJ) * 16 + cl;
#pragma unroll
      for (int r = 0; r < 4; r++) {
        float v = acc[i][j][r];
        if (Cb) Cb[(size_t)(row + r) * N + col] = f2bf(v);
        else    Cf[(size_t)(row + r) * N + col] = v;
      }
    }
}

// ---------------- fused RoPE + L2 norm (in place, bf16, strided) -------------
__global__ __launch_bounds__(256) void rope_l2norm(
    u16* __restrict__ x, const int* __restrict__ pos_ids,
    const float* __restrict__ scale, int hmask, int hshift, int stride) {
  const int lane = threadIdx.x & 63;
  const int wv = threadIdx.x >> 6;
  const int idx = blockIdx.x * 4 + wv;
  const int s = idx >> hshift;
  const int h = idx & hmask;
  u16* p = x + (size_t)s * stride + h * HD;
  const float pos = (float)pos_ids[s];
  const float inv = expf((float)lane * -0.20503692777194264f);  // 5e5^(-d/64)
  float sn, cs;
  sincosf(pos * inv, &sn, &cs);
  float a = bf2f(p[lane]);
  float b = bf2f(p[lane + 64]);
  float ra = a * cs - b * sn;
  float rb = b * cs + a * sn;
  float ss = ra * ra + rb * rb;
#pragma unroll
  for (int off = 32; off >= 1; off >>= 1) ss += __shfl_xor(ss, off, 64);
  float rd = 1.0f / (sqrtf(ss) + 1e-6f);
  p[lane] = f2bf(scale[lane] * ra * rd);
  p[lane + 64] = f2bf(scale[lane + 64] * rb * rd);
}

// ---------------- V transpose: qkv V-cols [2048][1024@QS] -> [1024][2048] ----
__global__ __launch_bounds__(256) void transpose_v(const u16* __restrict__ v,
                                                   u16* __restrict__ vt) {
  __shared__ u16 t[64][65];
  const int r = threadIdx.x >> 6;
  const int c = threadIdx.x & 63;
  const int s0 = blockIdx.x * 64, d0 = blockIdx.y * 64;
#pragma unroll
  for (int i = 0; i < 16; i++) {
    int row = i * 4 + r;
    t[row][c] = v[(size_t)(s0 + row) * QS + d0 + c];
  }
  __syncthreads();
#pragma unroll
  for (int i = 0; i < 16; i++) {
    int row = i * 4 + r;
    vt[(size_t)(d0 + row) * S_LEN + s0 + c] = t[c][row];
  }
}

// ---------------- causal flash attention, Q-tile 128, 8 waves ----------------
// Work-balanced (qbi, 15-qbi) pairs, grid 8 x 32 = 256 blocks = 1/CU.
// K/V double-buffered in dynamic LDS; stage(kt+1) issued BEFORE compute(kt)
// (issue-early / wait-late): one vmcnt(0)+barrier per tile, stage latency
// hidden under a full compute phase.
#define PLD 68

__global__ __launch_bounds__(512) void flash_attn(
    const u16* __restrict__ QKV, const u16* __restrict__ Vt,
    u16* __restrict__ O) {
  extern __shared__ u16 alds[];
  u16* Ks = alds;           // [2][64*128]  slot = row*16 + (g ^ (row&15))
  u16* Vs = alds + 16384;   // [2][128*64]  slot = row*8  + (g ^ (row&7))
  u16* Ps = alds + 32768;   // [128][PLD]
  const int tid = threadIdx.x;
  const int lane = tid & 63, wv = tid >> 6;  // wv in [0,8)
  const int cl = lane & 15, qd = lane >> 4;
  const int h = blockIdx.y;
  const int kvh = h >> 2;
  const float es = 0.12751629240081506f;  // (1/sqrt(128)) * log2(e)

  const u16* Kbase = QKV + 4096 + kvh * HD;          // key rows, stride QS
  const u16* Vbase = Vt + (size_t)kvh * HD * S_LEN;  // [d][s], stride S_LEN

  auto stage = [&](int kt, int d) {
#pragma unroll
    for (int q = 0; q < 2; q++) {
      int c = q * 512 + wv * 64 + lane;
      int kr = c >> 4, kg = (c & 15) ^ (kr & 15);
      async16(Kbase + (size_t)(kt * 64 + kr) * QS + kg * 8,
              Ks + d * 8192 + (q * 512 + wv * 64) * 8);
      int vr = c >> 3, vg = (c & 7) ^ (vr & 7);
      async16(Vbase + (size_t)vr * S_LEN + kt * 64 + vg * 8,
              Vs + d * 8192 + (q * 512 + wv * 64) * 8);
    }
  };

  for (int half = 0; half < 2; half++) {
    const int qbi = half ? (15 - (int)blockIdx.x) : (int)blockIdx.x;
    const int q0 = qbi * 128;

    // Q fragments straight from global; wave wv owns q-rows q0+wv*16 .. +15
    bf16x8 aQ[4];
    {
      const u16* qrow =
          QKV + (size_t)(q0 + wv * 16 + cl) * QS + h * HD + qd * 8;
#pragma unroll
      for (int kk = 0; kk < 4; kk++) aQ[kk] = *(const bf16x8*)(qrow + kk * 32);
    }

    f32x4 oacc[8];
    f32x4 zz = {0.f, 0.f, 0.f, 0.f};
#pragma unroll
    for (int n = 0; n < 8; n++) oacc[n] = zz;
    float lsum[4] = {0.f, 0.f, 0.f, 0.f};

    const int row_min = q0 + wv * 16;
    const int ktmax = 2 * qbi + 1;  // >= 1 always

    int cur = 0;
    stage(0, 0);
    for (int kt = 0; kt <= ktmax; kt++) {
      if (kt < ktmax) stage(kt + 1, cur ^ 1);  // issue-early
      if (kt == 0) {
        VMC(4);  // tile0 landed; tile1's 4 loads stay in flight
        SB;
        BAR;
      }
      const int koff = cur * 8192;

      if (kt * 64 <= row_min + 15) {  // wave not fully above the diagonal
        // S = Q K^T (this wave: 16 q-rows x 64 keys)
        f32x4 sacc[4];
#pragma unroll
        for (int j = 0; j < 4; j++) sacc[j] = zz;
#pragma unroll
        for (int j = 0; j < 4; j++) {
          int row = j * 16 + cl;
#pragma unroll
          for (int kk = 0; kk < 4; kk++) {
            int ch = (kk * 4 + qd) ^ (row & 15);
            bf16x8 bK = *(const bf16x8*)&Ks[koff + row * 128 + ch * 8];
            sacc[j] = mfma16(aQ[kk], bK, sacc[j]);
          }
        }

        float pm[4][4];
        if (kt * 64 + 63 > row_min) {  // diagonal tile: causal mask
          const int grow = row_min + qd * 4;
#pragma unroll
          for (int j = 0; j < 4; j++) {
            int gcol = kt * 64 + j * 16 + cl;
#pragma unroll
            for (int r = 0; r < 4; r++)
              pm[j][r] = (gcol <= grow + r) ? EXP2(sacc[j][r] * es) : 0.f;
          }
        } else {
#pragma unroll
          for (int j = 0; j < 4; j++)
#pragma unroll
            for (int r = 0; r < 4; r++) pm[j][r] = EXP2(sacc[j][r] * es);
        }
#pragma unroll
        for (int j = 0; j < 4; j++)
#pragma unroll
          for (int r = 0; r < 4; r++) lsum[r] += pm[j][r];

        // P: C-layout -> LDS (A-layout); wave-private strip, no block barrier
#pragma unroll
        for (int j = 0; j < 4; j++)
#pragma unroll
          for (int r = 0; r < 4; r++)
            Ps[(wv * 16 + qd * 4 + r) * PLD + j * 16 + cl] = f2bf(pm[j][r]);
        __asm__ volatile("s_waitcnt lgkmcnt(0)" ::: "memory");

        // O += P V
#pragma unroll
        for (int kk = 0; kk < 2; kk++) {
          bf16x8 aP =
              *(const bf16x8*)&Ps[(wv * 16 + cl) * PLD + kk * 32 + qd * 8];
#pragma unroll
          for (int n = 0; n < 8; n++) {
            int row = n * 16 + cl;
            int ch = (kk * 4 + qd) ^ (row & 7);
            bf16x8 bV = *(const bf16x8*)&Vs[koff + row * 64 + ch * 8];
            oacc[n] = mfma16(aP, bV, oacc[n]);
          }
        }
      }

      VMC(0);  // stage(kt+1) drained (latency hidden under compute)
      SB;
      BAR;
      cur ^= 1;
    }

    // reduce row sums across the 16-lane column group, write O
#pragma unroll
    for (int r = 0; r < 4; r++) {
#pragma unroll
      for (int off = 8; off >= 1; off >>= 1)
        lsum[r] += __shfl_xor(lsum[r], off, 64);
    }
#pragma unroll
    for (int r = 0; r < 4; r++) {
      float il = 1.0f / lsum[r];
      int row = row_min + qd * 4 + r;
#pragma unroll
      for (int n = 0; n < 8; n++)
        O[(size_t)row * HID + h * HD + n * 16 + cl] = f2bf(oacc[n][r] * il);
    }
  }
}

// ---------------- launch ----------------
extern "C" void kernel_launch(void* const* d_in, const int* in_sizes, int n_in,
                              void* d_out, int out_size, void* d_ws, size_t ws_size,
                              hipStream_t stream) {
  const float* hs = (const float*)d_in[0];
  const int* pos = (const int*)d_in[1];
  const float* Wq = (const float*)d_in[2];
  const float* Wk = (const float*)d_in[3];
  const float* Wv = (const float*)d_in[4];
  const float* Wo = (const float*)d_in[5];
  const float* qsc = (const float*)d_in[6];
  const float* ksc = (const float*)d_in[7];
  float* out = (float*)d_out;
  char* ws = (char*)d_ws;
  const size_t MB = 1u << 20;

  u16* hs_b  = (u16*)(ws + 0 * MB);   // 16 MB; reused for attention output
  u16* wq_b  = (u16*)(ws + 16 * MB);  // 32 MB  } wq|wk|wv contiguous ->
  u16* wk_b  = (u16*)(ws + 48 * MB);  // 8 MB   }   B[6144][4096]
  u16* wv_b  = (u16*)(ws + 56 * MB);  // 8 MB   }
  u16* qkv_b = (u16*)(ws + 64 * MB);  // 24 MB: [2048][6144] = Q|K|V
  u16* vt_b  = (u16*)(ws + 88 * MB);  // 4 MB: V^T [1024][2048]
  u16* wo_b  = (u16*)(ws + 92 * MB);  // 32 MB
  u16* o_b   = hs_b;                  // hs dead after qkv gemm

  static bool attr_set = false;
  if (!attr_set) {
    hipFuncSetAttribute(reinterpret_cast<const void*>(&gemm8p<3>),
                        hipFuncAttributeMaxDynamicSharedMemorySize, 114688);
    hipFuncSetAttribute(reinterpret_cast<const void*>(&gemm8p<2>),
                        hipFuncAttributeMaxDynamicSharedMemorySize, 98304);
    hipFuncSetAttribute(reinterpret_cast<const void*>(&flash_attn),
                        hipFuncAttributeMaxDynamicSharedMemorySize, 82944);
    attr_set = true;
  }

  conv_all<<<49152, 256, 0, stream>>>(hs, Wq, Wk, Wv, Wo,
                                      hs_b, wq_b, wk_b, wv_b, wo_b);

  // fused QKV projection: [2048][4096] x [6144][4096]^T -> [2048][6144]
  // BN=192 -> grid 8 x 32 = 256 blocks = 1/CU exactly
  gemm8p<3><<<dim3(8 * (QS / 192)), 512, 114688, stream>>>(
      hs_b, wq_b, qkv_b, nullptr, QS, HID);

  rope_l2norm<<<S_LEN * NH / 4, 256, 0, stream>>>(qkv_b, pos, qsc, NH - 1, 5, QS);
  rope_l2norm<<<S_LEN * NKV / 4, 256, 0, stream>>>(qkv_b + 4096, pos, ksc, NKV - 1, 3, QS);
  transpose_v<<<dim3(S_LEN / 64, (NKV * HD) / 64), 256, 0, stream>>>(qkv_b + 5120, vt_b);

  flash_attn<<<dim3(8, NH), 512, 82944, stream>>>(qkv_b, vt_b, o_b);

  // output projection: [2048][4096] x [4096][4096]^T -> f32 out
  // BN=128 -> grid 8 x 32 = 256 blocks = 1/CU exactly
  gemm8p<2><<<dim3(8 * (HID / 128)), 512, 98304, stream>>>(
      o_b, wo_b, nullptr, out, HID, HID);
}

// Round 5
// 457.258 us; speedup vs baseline: 1.0186x; 1.0186x over previous
//
#include <hip/hip_runtime.h>
#include <math.h>

typedef unsigned short u16;
typedef unsigned int u32;
typedef __attribute__((ext_vector_type(8))) short bf16x8;
typedef __attribute__((ext_vector_type(4))) float f32x4;

#define S_LEN 2048
#define HID 4096
#define NH 32
#define NKV 8
#define HD 128
#define QS 6144  // fused qkv row stride (4096 Q | 1024 K | 1024 V)

__device__ __forceinline__ u16 f2bf(float f) {
  u32 u = __float_as_uint(f);
  u32 r = (u + 0x7FFFu + ((u >> 16) & 1u)) >> 16;
  return (u16)r;
}
__device__ __forceinline__ float bf2f(u16 v) {
  return __uint_as_float(((u32)v) << 16);
}
__device__ __forceinline__ f32x4 mfma16(bf16x8 a, bf16x8 b, f32x4 c) {
  return __builtin_amdgcn_mfma_f32_16x16x32_bf16(a, b, c, 0, 0, 0);
}
// async global->LDS, 16B per lane. LDS dest is wave-uniform base + lane*16.
__device__ __forceinline__ void async16(const u16* g, u16* l) {
  __builtin_amdgcn_global_load_lds(
      (__attribute__((address_space(1))) void*)g,
      (__attribute__((address_space(3))) void*)l, 16, 0, 0);
}
#if __has_builtin(__builtin_amdgcn_exp2f)
#define EXP2(x) __builtin_amdgcn_exp2f(x)
#else
#define EXP2(x) exp2f(x)
#endif

#define VMC(n) asm volatile("s_waitcnt vmcnt(" #n ")" ::: "memory")
#define LGKM(n) asm volatile("s_waitcnt lgkmcnt(" #n ")" ::: "memory")
#define SB __builtin_amdgcn_sched_barrier(0)
#define BAR __builtin_amdgcn_s_barrier()
#define P1 __builtin_amdgcn_s_setprio(1)
#define P0 __builtin_amdgcn_s_setprio(0)

// ---------------- fp32 -> bf16, all five tensors in one launch ---------------
__global__ __launch_bounds__(256) void conv_all(
    const float* __restrict__ hs, const float* __restrict__ wq,
    const float* __restrict__ wk, const float* __restrict__ wv,
    const float* __restrict__ wo, u16* __restrict__ dhs, u16* __restrict__ dwq,
    u16* __restrict__ dwk, u16* __restrict__ dwv, u16* __restrict__ dwo) {
  int i = blockIdx.x * 256 + threadIdx.x;
  const float* src;
  u16* dst;
  int off;
  if (i < 2097152) { src = hs; dst = dhs; off = 0; }
  else if (i < 6291456) { src = wq; dst = dwq; off = 2097152; }
  else if (i < 7340032) { src = wk; dst = dwk; off = 6291456; }
  else if (i < 8388608) { src = wv; dst = dwv; off = 7340032; }
  else { src = wo; dst = dwo; off = 8388608; }
  int j = i - off;
  float4 v = ((const float4*)src)[j];
  ushort4 o;
  o.x = f2bf(v.x); o.y = f2bf(v.y); o.z = f2bf(v.z); o.w = f2bf(v.w);
  ((ushort4*)dst)[j] = o;
}

// ---------------- 256xBN 4-macro-phase GEMM ---------------------------------
// C[M,N] = A[M,K] * B[N,K]^T.  BM=256, BN=NJ*64 (192 or 128), BK=64,
// 512 thr = 8 waves (4M x 2N, wave tile 64 x BN/2).  LDS dynamic:
// As[2][256][64] | Bs[2][BN][64] bf16, chunk-XOR swizzled on BOTH the
// pre-swizzled global source of global_load_lds (linear LDS dest) and the
// ds_read_b128 side.  R1/R2/R4 measured a CONSTANT ~530cyc/phase sync
// overhead independent of MFMA-cluster size -> amortize it: 4 phases per
// K-tile-pair, 24 MFMA/wave per phase (was 8 phases x 12).
// Counted VMC(4) at pre-ph2/pre-ph4 (drains exactly the next tile; newest
// A-prefetch stays in flight); VMC(0) only in the tail iteration.
// Grid = 8 * (N/BN)  (M == 2048 -> 8 M-tiles, exact multiple of 8 XCDs).

#define DSA(dst, qi, d)                                                    \
  {                                                                        \
    const u16* p_ = As + (d)*16384 + (wm * 64 + (qi)*32 + cl) * 64;        \
    _Pragma("unroll") for (int ii = 0; ii < 2; ii++)                       \
        _Pragma("unroll") for (int kk = 0; kk < 2; kk++)                   \
            dst[ii][kk] =                                                  \
        *(const bf16x8*)(p_ + ii * 1024 + ((c0 ^ (kk << 2)) << 3));        \
  }

#define DSB(dst, qj, d)                                                    \
  {                                                                        \
    const u16* p_ =                                                        \
        Bs + (d)*BSTR + (wn * (BN / 2) + (qj) * (BN / 4) + cl) * 64;       \
    _Pragma("unroll") for (int jj = 0; jj < NJ; jj++)                      \
        _Pragma("unroll") for (int kk = 0; kk < 2; kk++)                   \
            dst[jj][kk] =                                                  \
        *(const bf16x8*)(p_ + jj * 1024 + ((c0 ^ (kk << 2)) << 3));        \
  }

#define MM(qi, qj, asrc, bsrc)                                             \
  {                                                                        \
    _Pragma("unroll") for (int ii = 0; ii < 2; ii++)                       \
        _Pragma("unroll") for (int jj = 0; jj < NJ; jj++)                  \
            _Pragma("unroll") for (int kk = 0; kk < 2; kk++)               \
                acc[(qi)*2 + ii][(qj)*NJ + jj] =                           \
        mfma16(asrc[ii][kk], bsrc[jj][kk], acc[(qi)*2 + ii][(qj)*NJ + jj]);\
  }

// one macro-phase: entry barrier, drain ds, 24-MFMA cluster, exit barrier
#define PH2(MMA1, MMA2)                                          \
  {                                                              \
    BAR; LGKM(0); SB;                                            \
    P1; MMA1; MMA2; P0; SB; BAR;                                 \
  }

template <int NJ>
__global__ __launch_bounds__(512, 2) void gemm4p(
    const u16* __restrict__ A, const u16* __restrict__ B,
    u16* __restrict__ Cb, float* __restrict__ Cf, int N, int K) {
  constexpr int BN = NJ * 64;
  constexpr int BSTR = BN * 64;  // u16 per B dbuf
  extern __shared__ u16 lds[];
  u16* As = lds;           // [2][256*64]
  u16* Bs = lds + 32768;   // [2][BN*64]
  const int tid = threadIdx.x;
  const int lane = tid & 63, wv = tid >> 6;
  const int cl = lane & 15, qd = lane >> 4;
  const int wm = wv >> 1, wn = wv & 1;  // 4M x 2N waves
  const int c0 = qd ^ (cl & 7);

  // XCD-aware block swizzle (grid %8==0), decode M-fast (M-tiles == 8)
  const int cpx = gridDim.x >> 3;
  const int swz = (blockIdx.x & 7) * cpx + (blockIdx.x >> 3);
  const int m0 = (swz & 7) * 256;
  const int n0 = (swz >> 3) * BN;

  // per-lane staged-load source offsets (u16 elements); lane covers LDS
  // (row r, slot s), fetches global chunk c = s ^ (r&7)
  u32 aof[4], bof[NJ];
#pragma unroll
  for (int q = 0; q < 4; q++) {
    int r = q * 64 + wv * 8 + (lane >> 3);
    int c = (lane & 7) ^ (r & 7);
    aof[q] = (u32)(m0 + r) * K + c * 8;
  }
#pragma unroll
  for (int q = 0; q < NJ; q++) {
    int r = q * 64 + wv * 8 + (lane >> 3);
    int c = (lane & 7) ^ (r & 7);
    bof[q] = (u32)(n0 + r) * K + c * 8;
  }
  const int sbo = wv * 512;  // wave-uniform LDS stage offset

  auto STAll = [&](int tt, int d) {  // stage full A K-tile (4 loads)
#pragma unroll
    for (int q = 0; q < 4; q++)
      async16(A + (size_t)tt * 64 + aof[q], As + d * 16384 + q * 4096 + sbo);
  };
  auto STBall = [&](int tt, int d) {  // stage full B K-tile (NJ loads)
#pragma unroll
    for (int q = 0; q < NJ; q++)
      async16(B + (size_t)tt * 64 + bof[q], Bs + d * BSTR + q * 4096 + sbo);
  };

  f32x4 acc[4][2 * NJ];
  f32x4 zz = {0.f, 0.f, 0.f, 0.f};
#pragma unroll
  for (int i = 0; i < 4; i++)
#pragma unroll
    for (int j = 0; j < 2 * NJ; j++) acc[i][j] = zz;
  bf16x8 A0r[2][2], A1r[2][2], B0r[NJ][2], B1r[NJ][2];

  const int NT = K >> 6;  // 64-wide K-tiles; NT even, >= 4

  // prologue: t0 A+B -> dbuf0, t1 A -> dbuf1; drain t0 (t1A stays in flight)
  STAll(0, 0); STBall(0, 0); STAll(1, 1);
  VMC(4);
  SB;
  BAR;

  for (int it = 0; it < (NT >> 1); ++it) {
    const int t = it * 2;          // tiles t (dbuf0), t+1 (dbuf1)
    const bool s2 = (t + 2) < NT;  // NT even => also guards t+3
    // pre-ph1: ds A0,A1,B0 (dbuf0) | stage (t+1)B -> dbuf1 (freed prev ph4)
    DSA(A0r, 0, 0); DSA(A1r, 1, 0); DSB(B0r, 0, 0);
    STBall(t + 1, 1);
    // ph1: tile t, left half-K
    PH2(MM(0, 0, A0r, B0r), MM(1, 0, A1r, B0r));
    // pre-ph2: ds B1 (dbuf0) | stage (t+2)A -> dbuf0 (A freed at ph1 exit)
    //          VMC(4): drains (t+1)A+B exactly, leaves (t+2)A in flight
    DSB(B1r, 1, 0);
    if (s2) {
      STAll(t + 2, 0);
      VMC(4);
    } else {
      VMC(0);
    }
    // ph2: tile t, right half-K
    PH2(MM(0, 1, A0r, B1r), MM(1, 1, A1r, B1r));
    // pre-ph3: ds A0,A1,B0 (dbuf1; visible: VMC@pre-ph2 + ph2 entry barrier)
    //          stage (t+2)B -> dbuf0 (B freed at ph2 exit)
    DSA(A0r, 0, 1); DSA(A1r, 1, 1); DSB(B0r, 0, 1);
    if (s2) STBall(t + 2, 0);
    // ph3: tile t+1, left half-K
    PH2(MM(0, 0, A0r, B0r), MM(1, 0, A1r, B0r));
    // pre-ph4: ds B1 (dbuf1) | stage (t+3)A -> dbuf1 (A freed at ph3 exit)
    //          VMC(4): drains (t+2)A+B, leaves (t+3)A in flight
    DSB(B1r, 1, 1);
    if (s2) {
      STAll(t + 3, 1);
      VMC(4);
    } else {
      VMC(0);
    }
    // ph4: tile t+1, right half-K
    PH2(MM(0, 1, A0r, B1r), MM(1, 1, A1r, B1r));
  }

  // epilogue: C-write (C/D layout: col=lane&15, row=(lane>>4)*4+reg)
#pragma unroll
  for (int i = 0; i < 4; i++)
#pragma unroll
    for (int j = 0; j < 2 * NJ; j++) {
      int row = m0 + wm * 64 + i * 16 + qd * 4;
      int col = n0 + wn * (BN / 2) + (j / NJ) * (BN / 4) + (j % NJ) * 16 + cl;
#pragma unroll
      for (int r = 0; r < 4; r++) {
        float v = acc[i][j][r];
        if (Cb) Cb[(size_t)(row + r) * N + col] = f2bf(v);
        else    Cf[(size_t)(row + r) * N + col] = v;
      }
    }
}

// ---------------- fused RoPE + L2 norm (in place, bf16, strided) -------------
__global__ __launch_bounds__(256) void rope_l2norm(
    u16* __restrict__ x, const int* __restrict__ pos_ids,
    const float* __restrict__ scale, int hmask, int hshift, int stride) {
  const int lane = threadIdx.x & 63;
  const int wv = threadIdx.x >> 6;
  const int idx = blockIdx.x * 4 + wv;
  const int s = idx >> hshift;
  const int h = idx & hmask;
  u16* p = x + (size_t)s * stride + h * HD;
  const float pos = (float)pos_ids[s];
  const float inv = expf((float)lane * -0.20503692777194264f);  // 5e5^(-d/64)
  float sn, cs;
  sincosf(pos * inv, &sn, &cs);
  float a = bf2f(p[lane]);
  float b = bf2f(p[lane + 64]);
  float ra = a * cs - b * sn;
  float rb = b * cs + a * sn;
  float ss = ra * ra + rb * rb;
#pragma unroll
  for (int off = 32; off >= 1; off >>= 1) ss += __shfl_xor(ss, off, 64);
  float rd = 1.0f / (sqrtf(ss) + 1e-6f);
  p[lane] = f2bf(scale[lane] * ra * rd);
  p[lane + 64] = f2bf(scale[lane + 64] * rb * rd);
}

// ---------------- V transpose: qkv V-cols [2048][1024@QS] -> [1024][2048] ----
__global__ __launch_bounds__(256) void transpose_v(const u16* __restrict__ v,
                                                   u16* __restrict__ vt) {
  __shared__ u16 t[64][65];
  const int r = threadIdx.x >> 6;
  const int c = threadIdx.x & 63;
  const int s0 = blockIdx.x * 64, d0 = blockIdx.y * 64;
#pragma unroll
  for (int i = 0; i < 16; i++) {
    int row = i * 4 + r;
    t[row][c] = v[(size_t)(s0 + row) * QS + d0 + c];
  }
  __syncthreads();
#pragma unroll
  for (int i = 0; i < 16; i++) {
    int row = i * 4 + r;
    vt[(size_t)(d0 + row) * S_LEN + s0 + c] = t[c][row];
  }
}

// ---------------- causal flash attention, Q-tile 128, 8 waves ----------------
// Work-balanced (qbi, 15-qbi) pairs, grid 8 x 32 = 256 blocks = 1/CU.
// K/V double-buffered in dynamic LDS; stage(kt+1) issued BEFORE compute(kt)
// (issue-early / wait-late): one vmcnt(0)+barrier per tile, stage latency
// hidden under a full compute phase.
#define PLD 68

__global__ __launch_bounds__(512) void flash_attn(
    const u16* __restrict__ QKV, const u16* __restrict__ Vt,
    u16* __restrict__ O) {
  extern __shared__ u16 alds[];
  u16* Ks = alds;           // [2][64*128]  slot = row*16 + (g ^ (row&15))
  u16* Vs = alds + 16384;   // [2][128*64]  slot = row*8  + (g ^ (row&7))
  u16* Ps = alds + 32768;   // [128][PLD]
  const int tid = threadIdx.x;
  const int lane = tid & 63, wv = tid >> 6;  // wv in [0,8)
  const int cl = lane & 15, qd = lane >> 4;
  const int h = blockIdx.y;
  const int kvh = h >> 2;
  const float es = 0.12751629240081506f;  // (1/sqrt(128)) * log2(e)

  const u16* Kbase = QKV + 4096 + kvh * HD;          // key rows, stride QS
  const u16* Vbase = Vt + (size_t)kvh * HD * S_LEN;  // [d][s], stride S_LEN

  auto stage = [&](int kt, int d) {
#pragma unroll
    for (int q = 0; q < 2; q++) {
      int c = q * 512 + wv * 64 + lane;
      int kr = c >> 4, kg = (c & 15) ^ (kr & 15);
      async16(Kbase + (size_t)(kt * 64 + kr) * QS + kg * 8,
              Ks + d * 8192 + (q * 512 + wv * 64) * 8);
      int vr = c >> 3, vg = (c & 7) ^ (vr & 7);
      async16(Vbase + (size_t)vr * S_LEN + kt * 64 + vg * 8,
              Vs + d * 8192 + (q * 512 + wv * 64) * 8);
    }
  };

  for (int half = 0; half < 2; half++) {
    const int qbi = half ? (15 - (int)blockIdx.x) : (int)blockIdx.x;
    const int q0 = qbi * 128;

    // Q fragments straight from global; wave wv owns q-rows q0+wv*16 .. +15
    bf16x8 aQ[4];
    {
      const u16* qrow =
          QKV + (size_t)(q0 + wv * 16 + cl) * QS + h * HD + qd * 8;
#pragma unroll
      for (int kk = 0; kk < 4; kk++) aQ[kk] = *(const bf16x8*)(qrow + kk * 32);
    }

    f32x4 oacc[8];
    f32x4 zz = {0.f, 0.f, 0.f, 0.f};
#pragma unroll
    for (int n = 0; n < 8; n++) oacc[n] = zz;
    float lsum[4] = {0.f, 0.f, 0.f, 0.f};

    const int row_min = q0 + wv * 16;
    const int ktmax = 2 * qbi + 1;  // >= 1 always

    int cur = 0;
    stage(0, 0);
    for (int kt = 0; kt <= ktmax; kt++) {
      if (kt < ktmax) stage(kt + 1, cur ^ 1);  // issue-early
      if (kt == 0) {
        VMC(4);  // tile0 landed; tile1's 4 loads stay in flight
        SB;
        BAR;
      }
      const int koff = cur * 8192;

      if (kt * 64 <= row_min + 15) {  // wave not fully above the diagonal
        // S = Q K^T (this wave: 16 q-rows x 64 keys)
        f32x4 sacc[4];
#pragma unroll
        for (int j = 0; j < 4; j++) sacc[j] = zz;
#pragma unroll
        for (int j = 0; j < 4; j++) {
          int row = j * 16 + cl;
#pragma unroll
          for (int kk = 0; kk < 4; kk++) {
            int ch = (kk * 4 + qd) ^ (row & 15);
            bf16x8 bK = *(const bf16x8*)&Ks[koff + row * 128 + ch * 8];
            sacc[j] = mfma16(aQ[kk], bK, sacc[j]);
          }
        }

        float pm[4][4];
        if (kt * 64 + 63 > row_min) {  // diagonal tile: causal mask
          const int grow = row_min + qd * 4;
#pragma unroll
          for (int j = 0; j < 4; j++) {
            int gcol = kt * 64 + j * 16 + cl;
#pragma unroll
            for (int r = 0; r < 4; r++)
              pm[j][r] = (gcol <= grow + r) ? EXP2(sacc[j][r] * es) : 0.f;
          }
        } else {
#pragma unroll
          for (int j = 0; j < 4; j++)
#pragma unroll
            for (int r = 0; r < 4; r++) pm[j][r] = EXP2(sacc[j][r] * es);
        }
#pragma unroll
        for (int j = 0; j < 4; j++)
#pragma unroll
          for (int r = 0; r < 4; r++) lsum[r] += pm[j][r];

        // P: C-layout -> LDS (A-layout); wave-private strip, no block barrier
#pragma unroll
        for (int j = 0; j < 4; j++)
#pragma unroll
          for (int r = 0; r < 4; r++)
            Ps[(wv * 16 + qd * 4 + r) * PLD + j * 16 + cl] = f2bf(pm[j][r]);
        __asm__ volatile("s_waitcnt lgkmcnt(0)" ::: "memory");

        // O += P V
#pragma unroll
        for (int kk = 0; kk < 2; kk++) {
          bf16x8 aP =
              *(const bf16x8*)&Ps[(wv * 16 + cl) * PLD + kk * 32 + qd * 8];
#pragma unroll
          for (int n = 0; n < 8; n++) {
            int row = n * 16 + cl;
            int ch = (kk * 4 + qd) ^ (row & 7);
            bf16x8 bV = *(const bf16x8*)&Vs[koff + row * 64 + ch * 8];
            oacc[n] = mfma16(aP, bV, oacc[n]);
          }
        }
      }

      VMC(0);  // stage(kt+1) drained (latency hidden under compute)
      SB;
      BAR;
      cur ^= 1;
    }

    // reduce row sums across the 16-lane column group, write O
#pragma unroll
    for (int r = 0; r < 4; r++) {
#pragma unroll
      for (int off = 8; off >= 1; off >>= 1)
        lsum[r] += __shfl_xor(lsum[r], off, 64);
    }
#pragma unroll
    for (int r = 0; r < 4; r++) {
      float il = 1.0f / lsum[r];
      int row = row_min + qd * 4 + r;
#pragma unroll
      for (int n = 0; n < 8; n++)
        O[(size_t)row * HID + h * HD + n * 16 + cl] = f2bf(oacc[n][r] * il);
    }
  }
}

// ---------------- launch ----------------
extern "C" void kernel_launch(void* const* d_in, const int* in_sizes, int n_in,
                              void* d_out, int out_size, void* d_ws, size_t ws_size,
                              hipStream_t stream) {
  const float* hs = (const float*)d_in[0];
  const int* pos = (const int*)d_in[1];
  const float* Wq = (const float*)d_in[2];
  const float* Wk = (const float*)d_in[3];
  const float* Wv = (const float*)d_in[4];
  const float* Wo = (const float*)d_in[5];
  const float* qsc = (const float*)d_in[6];
  const float* ksc = (const float*)d_in[7];
  float* out = (float*)d_out;
  char* ws = (char*)d_ws;
  const size_t MB = 1u << 20;

  u16* hs_b  = (u16*)(ws + 0 * MB);   // 16 MB; reused for attention output
  u16* wq_b  = (u16*)(ws + 16 * MB);  // 32 MB  } wq|wk|wv contiguous ->
  u16* wk_b  = (u16*)(ws + 48 * MB);  // 8 MB   }   B[6144][4096]
  u16* wv_b  = (u16*)(ws + 56 * MB);  // 8 MB   }
  u16* qkv_b = (u16*)(ws + 64 * MB);  // 24 MB: [2048][6144] = Q|K|V
  u16* vt_b  = (u16*)(ws + 88 * MB);  // 4 MB: V^T [1024][2048]
  u16* wo_b  = (u16*)(ws + 92 * MB);  // 32 MB
  u16* o_b   = hs_b;                  // hs dead after qkv gemm

  static bool attr_set = false;
  if (!attr_set) {
    hipFuncSetAttribute(reinterpret_cast<const void*>(&gemm4p<3>),
                        hipFuncAttributeMaxDynamicSharedMemorySize, 114688);
    hipFuncSetAttribute(reinterpret_cast<const void*>(&gemm4p<2>),
                        hipFuncAttributeMaxDynamicSharedMemorySize, 98304);
    hipFuncSetAttribute(reinterpret_cast<const void*>(&flash_attn),
                        hipFuncAttributeMaxDynamicSharedMemorySize, 82944);
    attr_set = true;
  }

  conv_all<<<49152, 256, 0, stream>>>(hs, Wq, Wk, Wv, Wo,
                                      hs_b, wq_b, wk_b, wv_b, wo_b);

  // fused QKV projection: [2048][4096] x [6144][4096]^T -> [2048][6144]
  // BN=192 -> grid 8 x 32 = 256 blocks = 1/CU exactly
  gemm4p<3><<<dim3(8 * (QS / 192)), 512, 114688, stream>>>(
      hs_b, wq_b, qkv_b, nullptr, QS, HID);

  rope_l2norm<<<S_LEN * NH / 4, 256, 0, stream>>>(qkv_b, pos, qsc, NH - 1, 5, QS);
  rope_l2norm<<<S_LEN * NKV / 4, 256, 0, stream>>>(qkv_b + 4096, pos, ksc, NKV - 1, 3, QS);
  transpose_v<<<dim3(S_LEN / 64, (NKV * HD) / 64), 256, 0, stream>>>(qkv_b + 5120, vt_b);

  flash_attn<<<dim3(8, NH), 512, 82944, stream>>>(qkv_b, vt_b, o_b);

  // output projection: [2048][4096] x [4096][4096]^T -> f32 out
  // BN=128 -> grid 8 x 32 = 256 blocks = 1/CU exactly
  gemm4p<2><<<dim3(8 * (HID / 128)), 512, 98304, stream>>>(
      o_b, wo_b, nullptr, out, HID, HID);
}

// Round 6
// 454.071 us; speedup vs baseline: 1.0257x; 1.0070x over previous
//
#include <hip/hip_runtime.h>
#include <math.h>

typedef unsigned short u16;
typedef unsigned int u32;
typedef __attribute__((ext_vector_type(8))) short bf16x8;
typedef __attribute__((ext_vector_type(4))) float f32x4;

#define S_LEN 2048
#define HID 4096
#define NH 32
#define NKV 8
#define HD 128
#define QS 6144  // fused qkv row stride (4096 Q | 1024 K | 1024 V)

__device__ __forceinline__ u16 f2bf(float f) {
  u32 u = __float_as_uint(f);
  u32 r = (u + 0x7FFFu + ((u >> 16) & 1u)) >> 16;
  return (u16)r;
}
__device__ __forceinline__ float bf2f(u16 v) {
  return __uint_as_float(((u32)v) << 16);
}
__device__ __forceinline__ f32x4 mfma16(bf16x8 a, bf16x8 b, f32x4 c) {
  return __builtin_amdgcn_mfma_f32_16x16x32_bf16(a, b, c, 0, 0, 0);
}
// async global->LDS, 16B per lane. LDS dest is wave-uniform base + lane*16.
__device__ __forceinline__ void async16(const u16* g, u16* l) {
  __builtin_amdgcn_global_load_lds(
      (__attribute__((address_space(1))) void*)g,
      (__attribute__((address_space(3))) void*)l, 16, 0, 0);
}
#if __has_builtin(__builtin_amdgcn_exp2f)
#define EXP2(x) __builtin_amdgcn_exp2f(x)
#else
#define EXP2(x) exp2f(x)
#endif

#define VMC(n) asm volatile("s_waitcnt vmcnt(" #n ")" ::: "memory")
#define LGKM(n) asm volatile("s_waitcnt lgkmcnt(" #n ")" ::: "memory")
#define SB __builtin_amdgcn_sched_barrier(0)
#define BAR __builtin_amdgcn_s_barrier()
#define P1 __builtin_amdgcn_s_setprio(1)
#define P0 __builtin_amdgcn_s_setprio(0)

// ---------------- fp32 -> bf16, all five tensors in one launch ---------------
__global__ __launch_bounds__(256) void conv_all(
    const float* __restrict__ hs, const float* __restrict__ wq,
    const float* __restrict__ wk, const float* __restrict__ wv,
    const float* __restrict__ wo, u16* __restrict__ dhs, u16* __restrict__ dwq,
    u16* __restrict__ dwk, u16* __restrict__ dwv, u16* __restrict__ dwo) {
  int i = blockIdx.x * 256 + threadIdx.x;
  const float* src;
  u16* dst;
  int off;
  if (i < 2097152) { src = hs; dst = dhs; off = 0; }
  else if (i < 6291456) { src = wq; dst = dwq; off = 2097152; }
  else if (i < 7340032) { src = wk; dst = dwk; off = 6291456; }
  else if (i < 8388608) { src = wv; dst = dwv; off = 7340032; }
  else { src = wo; dst = dwo; off = 8388608; }
  int j = i - off;
  float4 v = ((const float4*)src)[j];
  ushort4 o;
  o.x = f2bf(v.x); o.y = f2bf(v.y); o.z = f2bf(v.z); o.w = f2bf(v.w);
  ((ushort4*)dst)[j] = o;
}

// ---------------- 256xBN 4-macro-phase GEMM ---------------------------------
// C[M,N] = A[M,K] * B[N,K]^T.  BM=256, BN=NJ*64 (192 or 128), BK=64,
// 512 thr = 8 waves (4M x 2N, wave tile 64 x BN/2).  LDS dynamic:
// As[2][256][64] | Bs[2][BN][64] bf16, chunk-XOR swizzled on BOTH the
// pre-swizzled global source of global_load_lds (linear LDS dest) and the
// ds_read_b128 side.
// R1/R2/R5 cycle data fit ~2x the 19.4cyc/MFMA pipe rate across schedules:
// kk-innermost MM created back-to-back DEPENDENT MFMA pairs (same acc reg).
// Fix: kk OUTERMOST -> 2*NJ independent MFMAs between each acc reuse.
// Counted VMC(4) at pre-ph2/pre-ph4 (drains exactly the next tile; newest
// A-prefetch stays in flight); VMC(0) only in the tail iteration.
// Grid = 8 * (N/BN)  (M == 2048 -> 8 M-tiles, exact multiple of 8 XCDs).

#define DSA(dst, qi, d)                                                    \
  {                                                                        \
    const u16* p_ = As + (d)*16384 + (wm * 64 + (qi)*32 + cl) * 64;        \
    _Pragma("unroll") for (int ii = 0; ii < 2; ii++)                       \
        _Pragma("unroll") for (int kk = 0; kk < 2; kk++)                   \
            dst[ii][kk] =                                                  \
        *(const bf16x8*)(p_ + ii * 1024 + ((c0 ^ (kk << 2)) << 3));        \
  }

#define DSB(dst, qj, d)                                                    \
  {                                                                        \
    const u16* p_ =                                                        \
        Bs + (d)*BSTR + (wn * (BN / 2) + (qj) * (BN / 4) + cl) * 64;       \
    _Pragma("unroll") for (int jj = 0; jj < NJ; jj++)                      \
        _Pragma("unroll") for (int kk = 0; kk < 2; kk++)                   \
            dst[jj][kk] =                                                  \
        *(const bf16x8*)(p_ + jj * 1024 + ((c0 ^ (kk << 2)) << 3));        \
  }

// kk OUTERMOST: consecutive MFMAs hit distinct acc regs (dep distance 2*NJ)
#define MM(qi, qj, asrc, bsrc)                                             \
  {                                                                        \
    _Pragma("unroll") for (int kk = 0; kk < 2; kk++)                       \
        _Pragma("unroll") for (int ii = 0; ii < 2; ii++)                   \
            _Pragma("unroll") for (int jj = 0; jj < NJ; jj++)              \
                acc[(qi)*2 + ii][(qj)*NJ + jj] =                           \
        mfma16(asrc[ii][kk], bsrc[jj][kk], acc[(qi)*2 + ii][(qj)*NJ + jj]);\
  }

// one macro-phase: entry barrier, drain ds, 48-MFMA cluster, exit barrier
#define PH2(MMA1, MMA2)                                          \
  {                                                              \
    BAR; LGKM(0); SB;                                            \
    P1; MMA1; MMA2; P0; SB; BAR;                                 \
  }

template <int NJ>
__global__ __launch_bounds__(512, 2) void gemm4p(
    const u16* __restrict__ A, const u16* __restrict__ B,
    u16* __restrict__ Cb, float* __restrict__ Cf, int N, int K) {
  constexpr int BN = NJ * 64;
  constexpr int BSTR = BN * 64;  // u16 per B dbuf
  extern __shared__ u16 lds[];
  u16* As = lds;           // [2][256*64]
  u16* Bs = lds + 32768;   // [2][BN*64]
  const int tid = threadIdx.x;
  const int lane = tid & 63, wv = tid >> 6;
  const int cl = lane & 15, qd = lane >> 4;
  const int wm = wv >> 1, wn = wv & 1;  // 4M x 2N waves
  const int c0 = qd ^ (cl & 7);

  // XCD-aware block swizzle (grid %8==0), decode M-fast (M-tiles == 8)
  const int cpx = gridDim.x >> 3;
  const int swz = (blockIdx.x & 7) * cpx + (blockIdx.x >> 3);
  const int m0 = (swz & 7) * 256;
  const int n0 = (swz >> 3) * BN;

  // per-lane staged-load source offsets (u16 elements); lane covers LDS
  // (row r, slot s), fetches global chunk c = s ^ (r&7)
  u32 aof[4], bof[NJ];
#pragma unroll
  for (int q = 0; q < 4; q++) {
    int r = q * 64 + wv * 8 + (lane >> 3);
    int c = (lane & 7) ^ (r & 7);
    aof[q] = (u32)(m0 + r) * K + c * 8;
  }
#pragma unroll
  for (int q = 0; q < NJ; q++) {
    int r = q * 64 + wv * 8 + (lane >> 3);
    int c = (lane & 7) ^ (r & 7);
    bof[q] = (u32)(n0 + r) * K + c * 8;
  }
  const int sbo = wv * 512;  // wave-uniform LDS stage offset

  auto STAll = [&](int tt, int d) {  // stage full A K-tile (4 loads)
#pragma unroll
    for (int q = 0; q < 4; q++)
      async16(A + (size_t)tt * 64 + aof[q], As + d * 16384 + q * 4096 + sbo);
  };
  auto STBall = [&](int tt, int d) {  // stage full B K-tile (NJ loads)
#pragma unroll
    for (int q = 0; q < NJ; q++)
      async16(B + (size_t)tt * 64 + bof[q], Bs + d * BSTR + q * 4096 + sbo);
  };

  f32x4 acc[4][2 * NJ];
  f32x4 zz = {0.f, 0.f, 0.f, 0.f};
#pragma unroll
  for (int i = 0; i < 4; i++)
#pragma unroll
    for (int j = 0; j < 2 * NJ; j++) acc[i][j] = zz;
  bf16x8 A0r[2][2], A1r[2][2], B0r[NJ][2], B1r[NJ][2];

  const int NT = K >> 6;  // 64-wide K-tiles; NT even, >= 4

  // prologue: t0 A+B -> dbuf0, t1 A -> dbuf1; drain t0 (t1A stays in flight)
  STAll(0, 0); STBall(0, 0); STAll(1, 1);
  VMC(4);
  SB;
  BAR;

  for (int it = 0; it < (NT >> 1); ++it) {
    const int t = it * 2;          // tiles t (dbuf0), t+1 (dbuf1)
    const bool s2 = (t + 2) < NT;  // NT even => also guards t+3
    // pre-ph1: ds A0,A1,B0 (dbuf0) | stage (t+1)B -> dbuf1 (freed prev ph4)
    DSA(A0r, 0, 0); DSA(A1r, 1, 0); DSB(B0r, 0, 0);
    STBall(t + 1, 1);
    // ph1: tile t, left half-K
    PH2(MM(0, 0, A0r, B0r), MM(1, 0, A1r, B0r));
    // pre-ph2: ds B1 (dbuf0) | stage (t+2)A -> dbuf0 (A freed at ph1 exit)
    //          VMC(4): drains (t+1)A+B exactly, leaves (t+2)A in flight
    DSB(B1r, 1, 0);
    if (s2) {
      STAll(t + 2, 0);
      VMC(4);
    } else {
      VMC(0);
    }
    // ph2: tile t, right half-K
    PH2(MM(0, 1, A0r, B1r), MM(1, 1, A1r, B1r));
    // pre-ph3: ds A0,A1,B0 (dbuf1; visible: VMC@pre-ph2 + ph2 entry barrier)
    //          stage (t+2)B -> dbuf0 (B freed at ph2 exit)
    DSA(A0r, 0, 1); DSA(A1r, 1, 1); DSB(B0r, 0, 1);
    if (s2) STBall(t + 2, 0);
    // ph3: tile t+1, left half-K
    PH2(MM(0, 0, A0r, B0r), MM(1, 0, A1r, B0r));
    // pre-ph4: ds B1 (dbuf1) | stage (t+3)A -> dbuf1 (A freed at ph3 exit)
    //          VMC(4): drains (t+2)A+B, leaves (t+3)A in flight
    DSB(B1r, 1, 1);
    if (s2) {
      STAll(t + 3, 1);
      VMC(4);
    } else {
      VMC(0);
    }
    // ph4: tile t+1, right half-K
    PH2(MM(0, 1, A0r, B1r), MM(1, 1, A1r, B1r));
  }

  // epilogue: C-write (C/D layout: col=lane&15, row=(lane>>4)*4+reg)
#pragma unroll
  for (int i = 0; i < 4; i++)
#pragma unroll
    for (int j = 0; j < 2 * NJ; j++) {
      int row = m0 + wm * 64 + i * 16 + qd * 4;
      int col = n0 + wn * (BN / 2) + (j / NJ) * (BN / 4) + (j % NJ) * 16 + cl;
#pragma unroll
      for (int r = 0; r < 4; r++) {
        float v = acc[i][j][r];
        if (Cb) Cb[(size_t)(row + r) * N + col] = f2bf(v);
        else    Cf[(size_t)(row + r) * N + col] = v;
      }
    }
}

// ---------------- fused RoPE + L2 norm (in place, bf16, strided) -------------
__global__ __launch_bounds__(256) void rope_l2norm(
    u16* __restrict__ x, const int* __restrict__ pos_ids,
    const float* __restrict__ scale, int hmask, int hshift, int stride) {
  const int lane = threadIdx.x & 63;
  const int wv = threadIdx.x >> 6;
  const int idx = blockIdx.x * 4 + wv;
  const int s = idx >> hshift;
  const int h = idx & hmask;
  u16* p = x + (size_t)s * stride + h * HD;
  const float pos = (float)pos_ids[s];
  const float inv = expf((float)lane * -0.20503692777194264f);  // 5e5^(-d/64)
  float sn, cs;
  sincosf(pos * inv, &sn, &cs);
  float a = bf2f(p[lane]);
  float b = bf2f(p[lane + 64]);
  float ra = a * cs - b * sn;
  float rb = b * cs + a * sn;
  float ss = ra * ra + rb * rb;
#pragma unroll
  for (int off = 32; off >= 1; off >>= 1) ss += __shfl_xor(ss, off, 64);
  float rd = 1.0f / (sqrtf(ss) + 1e-6f);
  p[lane] = f2bf(scale[lane] * ra * rd);
  p[lane + 64] = f2bf(scale[lane + 64] * rb * rd);
}

// ---------------- V transpose: qkv V-cols [2048][1024@QS] -> [1024][2048] ----
__global__ __launch_bounds__(256) void transpose_v(const u16* __restrict__ v,
                                                   u16* __restrict__ vt) {
  __shared__ u16 t[64][65];
  const int r = threadIdx.x >> 6;
  const int c = threadIdx.x & 63;
  const int s0 = blockIdx.x * 64, d0 = blockIdx.y * 64;
#pragma unroll
  for (int i = 0; i < 16; i++) {
    int row = i * 4 + r;
    t[row][c] = v[(size_t)(s0 + row) * QS + d0 + c];
  }
  __syncthreads();
#pragma unroll
  for (int i = 0; i < 16; i++) {
    int row = i * 4 + r;
    vt[(size_t)(d0 + row) * S_LEN + s0 + c] = t[c][row];
  }
}

// ---------------- causal flash attention, Q-tile 128, 8 waves ----------------
// Work-balanced (qbi, 15-qbi) pairs, grid 8 x 32 = 256 blocks = 1/CU.
// K/V double-buffered in dynamic LDS; stage(kt+1) issued BEFORE compute(kt)
// (issue-early / wait-late): one vmcnt(0)+barrier per tile, stage latency
// hidden under a full compute phase.  QK^T: kk outermost (dep distance 4).
#define PLD 68

__global__ __launch_bounds__(512) void flash_attn(
    const u16* __restrict__ QKV, const u16* __restrict__ Vt,
    u16* __restrict__ O) {
  extern __shared__ u16 alds[];
  u16* Ks = alds;           // [2][64*128]  slot = row*16 + (g ^ (row&15))
  u16* Vs = alds + 16384;   // [2][128*64]  slot = row*8  + (g ^ (row&7))
  u16* Ps = alds + 32768;   // [128][PLD]
  const int tid = threadIdx.x;
  const int lane = tid & 63, wv = tid >> 6;  // wv in [0,8)
  const int cl = lane & 15, qd = lane >> 4;
  const int h = blockIdx.y;
  const int kvh = h >> 2;
  const float es = 0.12751629240081506f;  // (1/sqrt(128)) * log2(e)

  const u16* Kbase = QKV + 4096 + kvh * HD;          // key rows, stride QS
  const u16* Vbase = Vt + (size_t)kvh * HD * S_LEN;  // [d][s], stride S_LEN

  auto stage = [&](int kt, int d) {
#pragma unroll
    for (int q = 0; q < 2; q++) {
      int c = q * 512 + wv * 64 + lane;
      int kr = c >> 4, kg = (c & 15) ^ (kr & 15);
      async16(Kbase + (size_t)(kt * 64 + kr) * QS + kg * 8,
              Ks + d * 8192 + (q * 512 + wv * 64) * 8);
      int vr = c >> 3, vg = (c & 7) ^ (vr & 7);
      async16(Vbase + (size_t)vr * S_LEN + kt * 64 + vg * 8,
              Vs + d * 8192 + (q * 512 + wv * 64) * 8);
    }
  };

  for (int half = 0; half < 2; half++) {
    const int qbi = half ? (15 - (int)blockIdx.x) : (int)blockIdx.x;
    const int q0 = qbi * 128;

    // Q fragments straight from global; wave wv owns q-rows q0+wv*16 .. +15
    bf16x8 aQ[4];
    {
      const u16* qrow =
          QKV + (size_t)(q0 + wv * 16 + cl) * QS + h * HD + qd * 8;
#pragma unroll
      for (int kk = 0; kk < 4; kk++) aQ[kk] = *(const bf16x8*)(qrow + kk * 32);
    }

    f32x4 oacc[8];
    f32x4 zz = {0.f, 0.f, 0.f, 0.f};
#pragma unroll
    for (int n = 0; n < 8; n++) oacc[n] = zz;
    float lsum[4] = {0.f, 0.f, 0.f, 0.f};

    const int row_min = q0 + wv * 16;
    const int ktmax = 2 * qbi + 1;  // >= 1 always

    int cur = 0;
    stage(0, 0);
    for (int kt = 0; kt <= ktmax; kt++) {
      if (kt < ktmax) stage(kt + 1, cur ^ 1);  // issue-early
      if (kt == 0) {
        VMC(4);  // tile0 landed; tile1's 4 loads stay in flight
        SB;
        BAR;
      }
      const int koff = cur * 8192;

      if (kt * 64 <= row_min + 15) {  // wave not fully above the diagonal
        // S = Q K^T (this wave: 16 q-rows x 64 keys); kk outer -> indep runs
        f32x4 sacc[4];
#pragma unroll
        for (int j = 0; j < 4; j++) sacc[j] = zz;
#pragma unroll
        for (int kk = 0; kk < 4; kk++) {
#pragma unroll
          for (int j = 0; j < 4; j++) {
            int row = j * 16 + cl;
            int ch = (kk * 4 + qd) ^ (row & 15);
            bf16x8 bK = *(const bf16x8*)&Ks[koff + row * 128 + ch * 8];
            sacc[j] = mfma16(aQ[kk], bK, sacc[j]);
          }
        }

        float pm[4][4];
        if (kt * 64 + 63 > row_min) {  // diagonal tile: causal mask
          const int grow = row_min + qd * 4;
#pragma unroll
          for (int j = 0; j < 4; j++) {
            int gcol = kt * 64 + j * 16 + cl;
#pragma unroll
            for (int r = 0; r < 4; r++)
              pm[j][r] = (gcol <= grow + r) ? EXP2(sacc[j][r] * es) : 0.f;
          }
        } else {
#pragma unroll
          for (int j = 0; j < 4; j++)
#pragma unroll
            for (int r = 0; r < 4; r++) pm[j][r] = EXP2(sacc[j][r] * es);
        }
#pragma unroll
        for (int j = 0; j < 4; j++)
#pragma unroll
          for (int r = 0; r < 4; r++) lsum[r] += pm[j][r];

        // P: C-layout -> LDS (A-layout); wave-private strip, no block barrier
#pragma unroll
        for (int j = 0; j < 4; j++)
#pragma unroll
          for (int r = 0; r < 4; r++)
            Ps[(wv * 16 + qd * 4 + r) * PLD + j * 16 + cl] = f2bf(pm[j][r]);
        __asm__ volatile("s_waitcnt lgkmcnt(0)" ::: "memory");

        // O += P V (n inner: dep distance 8 already)
#pragma unroll
        for (int kk = 0; kk < 2; kk++) {
          bf16x8 aP =
              *(const bf16x8*)&Ps[(wv * 16 + cl) * PLD + kk * 32 + qd * 8];
#pragma unroll
          for (int n = 0; n < 8; n++) {
            int row = n * 16 + cl;
            int ch = (kk * 4 + qd) ^ (row & 7);
            bf16x8 bV = *(const bf16x8*)&Vs[koff + row * 64 + ch * 8];
            oacc[n] = mfma16(aP, bV, oacc[n]);
          }
        }
      }

      VMC(0);  // stage(kt+1) drained (latency hidden under compute)
      SB;
      BAR;
      cur ^= 1;
    }

    // reduce row sums across the 16-lane column group, write O
#pragma unroll
    for (int r = 0; r < 4; r++) {
#pragma unroll
      for (int off = 8; off >= 1; off >>= 1)
        lsum[r] += __shfl_xor(lsum[r], off, 64);
    }
#pragma unroll
    for (int r = 0; r < 4; r++) {
      float il = 1.0f / lsum[r];
      int row = row_min + qd * 4 + r;
#pragma unroll
      for (int n = 0; n < 8; n++)
        O[(size_t)row * HID + h * HD + n * 16 + cl] = f2bf(oacc[n][r] * il);
    }
  }
}

// ---------------- launch ----------------
extern "C" void kernel_launch(void* const* d_in, const int* in_sizes, int n_in,
                              void* d_out, int out_size, void* d_ws, size_t ws_size,
                              hipStream_t stream) {
  const float* hs = (const float*)d_in[0];
  const int* pos = (const int*)d_in[1];
  const float* Wq = (const float*)d_in[2];
  const float* Wk = (const float*)d_in[3];
  const float* Wv = (const float*)d_in[4];
  const float* Wo = (const float*)d_in[5];
  const float* qsc = (const float*)d_in[6];
  const float* ksc = (const float*)d_in[7];
  float* out = (float*)d_out;
  char* ws = (char*)d_ws;
  const size_t MB = 1u << 20;

  u16* hs_b  = (u16*)(ws + 0 * MB);   // 16 MB; reused for attention output
  u16* wq_b  = (u16*)(ws + 16 * MB);  // 32 MB  } wq|wk|wv contiguous ->
  u16* wk_b  = (u16*)(ws + 48 * MB);  // 8 MB   }   B[6144][4096]
  u16* wv_b  = (u16*)(ws + 56 * MB);  // 8 MB   }
  u16* qkv_b = (u16*)(ws + 64 * MB);  // 24 MB: [2048][6144] = Q|K|V
  u16* vt_b  = (u16*)(ws + 88 * MB);  // 4 MB: V^T [1024][2048]
  u16* wo_b  = (u16*)(ws + 92 * MB);  // 32 MB
  u16* o_b   = hs_b;                  // hs dead after qkv gemm

  static bool attr_set = false;
  if (!attr_set) {
    hipFuncSetAttribute(reinterpret_cast<const void*>(&gemm4p<3>),
                        hipFuncAttributeMaxDynamicSharedMemorySize, 114688);
    hipFuncSetAttribute(reinterpret_cast<const void*>(&gemm4p<2>),
                        hipFuncAttributeMaxDynamicSharedMemorySize, 98304);
    hipFuncSetAttribute(reinterpret_cast<const void*>(&flash_attn),
                        hipFuncAttributeMaxDynamicSharedMemorySize, 82944);
    attr_set = true;
  }

  conv_all<<<49152, 256, 0, stream>>>(hs, Wq, Wk, Wv, Wo,
                                      hs_b, wq_b, wk_b, wv_b, wo_b);

  // fused QKV projection: [2048][4096] x [6144][4096]^T -> [2048][6144]
  // BN=192 -> grid 8 x 32 = 256 blocks = 1/CU exactly
  gemm4p<3><<<dim3(8 * (QS / 192)), 512, 114688, stream>>>(
      hs_b, wq_b, qkv_b, nullptr, QS, HID);

  rope_l2norm<<<S_LEN * NH / 4, 256, 0, stream>>>(qkv_b, pos, qsc, NH - 1, 5, QS);
  rope_l2norm<<<S_LEN * NKV / 4, 256, 0, stream>>>(qkv_b + 4096, pos, ksc, NKV - 1, 3, QS);
  transpose_v<<<dim3(S_LEN / 64, (NKV * HD) / 64), 256, 0, stream>>>(qkv_b + 5120, vt_b);

  flash_attn<<<dim3(8, NH), 512, 82944, stream>>>(qkv_b, vt_b, o_b);

  // output projection: [2048][4096] x [4096][4096]^T -> f32 out
  // BN=128 -> grid 8 x 32 = 256 blocks = 1/CU exactly
  gemm4p<2><<<dim3(8 * (HID / 128)), 512, 98304, stream>>>(
      o_b, wo_b, nullptr, out, HID, HID);
}

// Round 7
// 448.897 us; speedup vs baseline: 1.0376x; 1.0115x over previous
//
#include <hip/hip_runtime.h>
#include <math.h>

typedef unsigned short u16;
typedef unsigned int u32;
typedef __attribute__((ext_vector_type(8))) short bf16x8;
typedef __attribute__((ext_vector_type(4))) float f32x4;

#define S_LEN 2048
#define HID 4096
#define NH 32
#define NKV 8
#define HD 128
#define QS 6144  // fused qkv row stride (4096 Q | 1024 K | 1024 V)

__device__ __forceinline__ u16 f2bf(float f) {
  u32 u = __float_as_uint(f);
  u32 r = (u + 0x7FFFu + ((u >> 16) & 1u)) >> 16;
  return (u16)r;
}
__device__ __forceinline__ float bf2f(u16 v) {
  return __uint_as_float(((u32)v) << 16);
}
__device__ __forceinline__ f32x4 mfma16(bf16x8 a, bf16x8 b, f32x4 c) {
  return __builtin_amdgcn_mfma_f32_16x16x32_bf16(a, b, c, 0, 0, 0);
}
// async global->LDS, 16B per lane. LDS dest is wave-uniform base + lane*16.
__device__ __forceinline__ void async16(const u16* g, u16* l) {
  __builtin_amdgcn_global_load_lds(
      (__attribute__((address_space(1))) void*)g,
      (__attribute__((address_space(3))) void*)l, 16, 0, 0);
}
#if __has_builtin(__builtin_amdgcn_exp2f)
#define EXP2(x) __builtin_amdgcn_exp2f(x)
#else
#define EXP2(x) exp2f(x)
#endif

#define VMC(n) asm volatile("s_waitcnt vmcnt(" #n ")" ::: "memory")
#define BAR __builtin_amdgcn_s_barrier()

// ---------------- fp32 -> bf16, all five tensors in one launch ---------------
__global__ __launch_bounds__(256) void conv_all(
    const float* __restrict__ hs, const float* __restrict__ wq,
    const float* __restrict__ wk, const float* __restrict__ wv,
    const float* __restrict__ wo, u16* __restrict__ dhs, u16* __restrict__ dwq,
    u16* __restrict__ dwk, u16* __restrict__ dwv, u16* __restrict__ dwo) {
  int i = blockIdx.x * 256 + threadIdx.x;
  const float* src;
  u16* dst;
  int off;
  if (i < 2097152) { src = hs; dst = dhs; off = 0; }
  else if (i < 6291456) { src = wq; dst = dwq; off = 2097152; }
  else if (i < 7340032) { src = wk; dst = dwk; off = 6291456; }
  else if (i < 8388608) { src = wv; dst = dwv; off = 7340032; }
  else { src = wo; dst = dwo; off = 8388608; }
  int j = i - off;
  float4 v = ((const float4*)src)[j];
  ushort4 o;
  o.x = f2bf(v.x); o.y = f2bf(v.y); o.z = f2bf(v.z); o.w = f2bf(v.w);
  ((ushort4*)dst)[j] = o;
}

// ---------------- 256xBN 4-macro-phase GEMM, compiler-scheduled -------------
// C[M,N] = A[M,K] * B[N,K]^T.  BM=256, BN=NJ*64 (192 or 128), BK=64,
// 512 thr = 8 waves (4M x 2N, wave tile 64 x BN/2).  LDS dynamic:
// As[2][256][64] | Bs[2][BN][64] bf16, chunk-XOR swizzled on BOTH the
// pre-swizzled global source of global_load_lds (linear LDS dest) and the
// ds_read_b128 side.
// R5/R6 post-mortem: the sched_barrier(0)+forced-LGKM(0) cage pinned all
// pre-phase DS/VALU outside the MFMA clusters (m141 pathology, 874->510 TF).
// This version removes ALL sched fences: barriers + counted VMC only.
// The compiler inserts exact counted lgkmcnt before first fragment use and
// interleaves addressing/DS issue into MFMA issue gaps (m97 behavior).
// Correctness: fragment ds_reads complete before their last in-phase use
// (compiler-enforced) -> before exit barrier -> buffer re-staged >=1 barrier
// later (WAR safe).  VMC's "memory" clobber stops upward hoisting of
// ds_reads past the gload_lds completion guard (RAW safe).
// Counted VMC(4) at pre-ph2/pre-ph4 drains exactly the next tile; VMC(0)
// only in the tail iteration.
// Grid = 8 * (N/BN)  (M == 2048 -> 8 M-tiles, exact multiple of 8 XCDs).

#define DSA(dst, qi, d)                                                    \
  {                                                                        \
    const u16* p_ = As + (d)*16384 + (wm * 64 + (qi)*32 + cl) * 64;        \
    _Pragma("unroll") for (int ii = 0; ii < 2; ii++)                       \
        _Pragma("unroll") for (int kk = 0; kk < 2; kk++)                   \
            dst[ii][kk] =                                                  \
        *(const bf16x8*)(p_ + ii * 1024 + ((c0 ^ (kk << 2)) << 3));        \
  }

#define DSB(dst, qj, d)                                                    \
  {                                                                        \
    const u16* p_ =                                                        \
        Bs + (d)*BSTR + (wn * (BN / 2) + (qj) * (BN / 4) + cl) * 64;       \
    _Pragma("unroll") for (int jj = 0; jj < NJ; jj++)                      \
        _Pragma("unroll") for (int kk = 0; kk < 2; kk++)                   \
            dst[jj][kk] =                                                  \
        *(const bf16x8*)(p_ + jj * 1024 + ((c0 ^ (kk << 2)) << 3));        \
  }

// kk outermost: consecutive MFMAs hit distinct acc regs
#define MM(qi, qj, asrc, bsrc)                                             \
  {                                                                        \
    _Pragma("unroll") for (int kk = 0; kk < 2; kk++)                       \
        _Pragma("unroll") for (int ii = 0; ii < 2; ii++)                   \
            _Pragma("unroll") for (int jj = 0; jj < NJ; jj++)              \
                acc[(qi)*2 + ii][(qj)*NJ + jj] =                           \
        mfma16(asrc[ii][kk], bsrc[jj][kk], acc[(qi)*2 + ii][(qj)*NJ + jj]);\
  }

// one macro-phase: just the barrier pair around the MFMA cluster.
// NO sched_barrier / explicit lgkm: let the compiler schedule.
#define PH2(MMA1, MMA2)                                          \
  {                                                              \
    BAR;                                                         \
    MMA1; MMA2;                                                  \
    BAR;                                                         \
  }

template <int NJ>
__global__ __launch_bounds__(512, 2) void gemm4p(
    const u16* __restrict__ A, const u16* __restrict__ B,
    u16* __restrict__ Cb, float* __restrict__ Cf, int N, int K) {
  constexpr int BN = NJ * 64;
  constexpr int BSTR = BN * 64;  // u16 per B dbuf
  extern __shared__ u16 lds[];
  u16* As = lds;           // [2][256*64]
  u16* Bs = lds + 32768;   // [2][BN*64]
  const int tid = threadIdx.x;
  const int lane = tid & 63, wv = tid >> 6;
  const int cl = lane & 15, qd = lane >> 4;
  const int wm = wv >> 1, wn = wv & 1;  // 4M x 2N waves
  const int c0 = qd ^ (cl & 7);

  // XCD-aware block swizzle (grid %8==0), decode M-fast (M-tiles == 8)
  const int cpx = gridDim.x >> 3;
  const int swz = (blockIdx.x & 7) * cpx + (blockIdx.x >> 3);
  const int m0 = (swz & 7) * 256;
  const int n0 = (swz >> 3) * BN;

  // per-lane staged-load source offsets (u16 elements); lane covers LDS
  // (row r, slot s), fetches global chunk c = s ^ (r&7)
  u32 aof[4], bof[NJ];
#pragma unroll
  for (int q = 0; q < 4; q++) {
    int r = q * 64 + wv * 8 + (lane >> 3);
    int c = (lane & 7) ^ (r & 7);
    aof[q] = (u32)(m0 + r) * K + c * 8;
  }
#pragma unroll
  for (int q = 0; q < NJ; q++) {
    int r = q * 64 + wv * 8 + (lane >> 3);
    int c = (lane & 7) ^ (r & 7);
    bof[q] = (u32)(n0 + r) * K + c * 8;
  }
  const int sbo = wv * 512;  // wave-uniform LDS stage offset

  auto STAll = [&](int tt, int d) {  // stage full A K-tile (4 loads)
#pragma unroll
    for (int q = 0; q < 4; q++)
      async16(A + (size_t)tt * 64 + aof[q], As + d * 16384 + q * 4096 + sbo);
  };
  auto STBall = [&](int tt, int d) {  // stage full B K-tile (NJ loads)
#pragma unroll
    for (int q = 0; q < NJ; q++)
      async16(B + (size_t)tt * 64 + bof[q], Bs + d * BSTR + q * 4096 + sbo);
  };

  f32x4 acc[4][2 * NJ];
  f32x4 zz = {0.f, 0.f, 0.f, 0.f};
#pragma unroll
  for (int i = 0; i < 4; i++)
#pragma unroll
    for (int j = 0; j < 2 * NJ; j++) acc[i][j] = zz;
  bf16x8 A0r[2][2], A1r[2][2], B0r[NJ][2], B1r[NJ][2];

  const int NT = K >> 6;  // 64-wide K-tiles; NT even, >= 4

  // prologue: t0 A+B -> dbuf0, t1 A -> dbuf1; drain t0 (t1A stays in flight)
  STAll(0, 0); STBall(0, 0); STAll(1, 1);
  VMC(4);
  BAR;

  for (int it = 0; it < (NT >> 1); ++it) {
    const int t = it * 2;          // tiles t (dbuf0), t+1 (dbuf1)
    const bool s2 = (t + 2) < NT;  // NT even => also guards t+3
    // pre-ph1: ds A0,A1,B0 (dbuf0) | stage (t+1)B -> dbuf1 (freed prev ph4)
    DSA(A0r, 0, 0); DSA(A1r, 1, 0); DSB(B0r, 0, 0);
    STBall(t + 1, 1);
    // ph1: tile t, left half-K
    PH2(MM(0, 0, A0r, B0r), MM(1, 0, A1r, B0r));
    // pre-ph2: ds B1 (dbuf0) | stage (t+2)A -> dbuf0 (A freed at ph1 exit)
    //          VMC(4): drains (t+1)A+B exactly, leaves (t+2)A in flight
    DSB(B1r, 1, 0);
    if (s2) {
      STAll(t + 2, 0);
      VMC(4);
    } else {
      VMC(0);
    }
    // ph2: tile t, right half-K
    PH2(MM(0, 1, A0r, B1r), MM(1, 1, A1r, B1r));
    // pre-ph3: ds A0,A1,B0 (dbuf1; visible: VMC@pre-ph2 + ph2 entry barrier)
    //          stage (t+2)B -> dbuf0 (B freed at ph2 exit)
    DSA(A0r, 0, 1); DSA(A1r, 1, 1); DSB(B0r, 0, 1);
    if (s2) STBall(t + 2, 0);
    // ph3: tile t+1, left half-K
    PH2(MM(0, 0, A0r, B0r), MM(1, 0, A1r, B0r));
    // pre-ph4: ds B1 (dbuf1) | stage (t+3)A -> dbuf1 (A freed at ph3 exit)
    //          VMC(4): drains (t+2)A+B, leaves (t+3)A in flight
    DSB(B1r, 1, 1);
    if (s2) {
      STAll(t + 3, 1);
      VMC(4);
    } else {
      VMC(0);
    }
    // ph4: tile t+1, right half-K
    PH2(MM(0, 1, A0r, B1r), MM(1, 1, A1r, B1r));
  }

  // epilogue: C-write (C/D layout: col=lane&15, row=(lane>>4)*4+reg)
#pragma unroll
  for (int i = 0; i < 4; i++)
#pragma unroll
    for (int j = 0; j < 2 * NJ; j++) {
      int row = m0 + wm * 64 + i * 16 + qd * 4;
      int col = n0 + wn * (BN / 2) + (j / NJ) * (BN / 4) + (j % NJ) * 16 + cl;
#pragma unroll
      for (int r = 0; r < 4; r++) {
        float v = acc[i][j][r];
        if (Cb) Cb[(size_t)(row + r) * N + col] = f2bf(v);
        else    Cf[(size_t)(row + r) * N + col] = v;
      }
    }
}

// ---------------- fused RoPE + L2 norm (in place, bf16, strided) -------------
__global__ __launch_bounds__(256) void rope_l2norm(
    u16* __restrict__ x, const int* __restrict__ pos_ids,
    const float* __restrict__ scale, int hmask, int hshift, int stride) {
  const int lane = threadIdx.x & 63;
  const int wv = threadIdx.x >> 6;
  const int idx = blockIdx.x * 4 + wv;
  const int s = idx >> hshift;
  const int h = idx & hmask;
  u16* p = x + (size_t)s * stride + h * HD;
  const float pos = (float)pos_ids[s];
  const float inv = expf((float)lane * -0.20503692777194264f);  // 5e5^(-d/64)
  float sn, cs;
  sincosf(pos * inv, &sn, &cs);
  float a = bf2f(p[lane]);
  float b = bf2f(p[lane + 64]);
  float ra = a * cs - b * sn;
  float rb = b * cs + a * sn;
  float ss = ra * ra + rb * rb;
#pragma unroll
  for (int off = 32; off >= 1; off >>= 1) ss += __shfl_xor(ss, off, 64);
  float rd = 1.0f / (sqrtf(ss) + 1e-6f);
  p[lane] = f2bf(scale[lane] * ra * rd);
  p[lane + 64] = f2bf(scale[lane + 64] * rb * rd);
}

// ---------------- V transpose: qkv V-cols [2048][1024@QS] -> [1024][2048] ----
__global__ __launch_bounds__(256) void transpose_v(const u16* __restrict__ v,
                                                   u16* __restrict__ vt) {
  __shared__ u16 t[64][65];
  const int r = threadIdx.x >> 6;
  const int c = threadIdx.x & 63;
  const int s0 = blockIdx.x * 64, d0 = blockIdx.y * 64;
#pragma unroll
  for (int i = 0; i < 16; i++) {
    int row = i * 4 + r;
    t[row][c] = v[(size_t)(s0 + row) * QS + d0 + c];
  }
  __syncthreads();
#pragma unroll
  for (int i = 0; i < 16; i++) {
    int row = i * 4 + r;
    vt[(size_t)(d0 + row) * S_LEN + s0 + c] = t[c][row];
  }
}

// ---------------- causal flash attention, Q-tile 128, 8 waves ----------------
// Work-balanced (qbi, 15-qbi) pairs, grid 8 x 32 = 256 blocks = 1/CU.
// K/V double-buffered in dynamic LDS; stage(kt+1) issued BEFORE compute(kt)
// (issue-early / wait-late): one vmcnt(0)+barrier per tile, stage latency
// hidden under a full compute phase.  No sched fences (compiler-scheduled).
#define PLD 68

__global__ __launch_bounds__(512) void flash_attn(
    const u16* __restrict__ QKV, const u16* __restrict__ Vt,
    u16* __restrict__ O) {
  extern __shared__ u16 alds[];
  u16* Ks = alds;           // [2][64*128]  slot = row*16 + (g ^ (row&15))
  u16* Vs = alds + 16384;   // [2][128*64]  slot = row*8  + (g ^ (row&7))
  u16* Ps = alds + 32768;   // [128][PLD]
  const int tid = threadIdx.x;
  const int lane = tid & 63, wv = tid >> 6;  // wv in [0,8)
  const int cl = lane & 15, qd = lane >> 4;
  const int h = blockIdx.y;
  const int kvh = h >> 2;
  const float es = 0.12751629240081506f;  // (1/sqrt(128)) * log2(e)

  const u16* Kbase = QKV + 4096 + kvh * HD;          // key rows, stride QS
  const u16* Vbase = Vt + (size_t)kvh * HD * S_LEN;  // [d][s], stride S_LEN

  auto stage = [&](int kt, int d) {
#pragma unroll
    for (int q = 0; q < 2; q++) {
      int c = q * 512 + wv * 64 + lane;
      int kr = c >> 4, kg = (c & 15) ^ (kr & 15);
      async16(Kbase + (size_t)(kt * 64 + kr) * QS + kg * 8,
              Ks + d * 8192 + (q * 512 + wv * 64) * 8);
      int vr = c >> 3, vg = (c & 7) ^ (vr & 7);
      async16(Vbase + (size_t)vr * S_LEN + kt * 64 + vg * 8,
              Vs + d * 8192 + (q * 512 + wv * 64) * 8);
    }
  };

  for (int half = 0; half < 2; half++) {
    const int qbi = half ? (15 - (int)blockIdx.x) : (int)blockIdx.x;
    const int q0 = qbi * 128;

    // Q fragments straight from global; wave wv owns q-rows q0+wv*16 .. +15
    bf16x8 aQ[4];
    {
      const u16* qrow =
          QKV + (size_t)(q0 + wv * 16 + cl) * QS + h * HD + qd * 8;
#pragma unroll
      for (int kk = 0; kk < 4; kk++) aQ[kk] = *(const bf16x8*)(qrow + kk * 32);
    }

    f32x4 oacc[8];
    f32x4 zz = {0.f, 0.f, 0.f, 0.f};
#pragma unroll
    for (int n = 0; n < 8; n++) oacc[n] = zz;
    float lsum[4] = {0.f, 0.f, 0.f, 0.f};

    const int row_min = q0 + wv * 16;
    const int ktmax = 2 * qbi + 1;  // >= 1 always

    int cur = 0;
    stage(0, 0);
    for (int kt = 0; kt <= ktmax; kt++) {
      if (kt < ktmax) stage(kt + 1, cur ^ 1);  // issue-early
      if (kt == 0) {
        VMC(4);  // tile0 landed; tile1's 4 loads stay in flight
        BAR;
      }
      const int koff = cur * 8192;

      if (kt * 64 <= row_min + 15) {  // wave not fully above the diagonal
        // S = Q K^T (this wave: 16 q-rows x 64 keys); kk outer -> indep runs
        f32x4 sacc[4];
#pragma unroll
        for (int j = 0; j < 4; j++) sacc[j] = zz;
#pragma unroll
        for (int kk = 0; kk < 4; kk++) {
#pragma unroll
          for (int j = 0; j < 4; j++) {
            int row = j * 16 + cl;
            int ch = (kk * 4 + qd) ^ (row & 15);
            bf16x8 bK = *(const bf16x8*)&Ks[koff + row * 128 + ch * 8];
            sacc[j] = mfma16(aQ[kk], bK, sacc[j]);
          }
        }

        float pm[4][4];
        if (kt * 64 + 63 > row_min) {  // diagonal tile: causal mask
          const int grow = row_min + qd * 4;
#pragma unroll
          for (int j = 0; j < 4; j++) {
            int gcol = kt * 64 + j * 16 + cl;
#pragma unroll
            for (int r = 0; r < 4; r++)
              pm[j][r] = (gcol <= grow + r) ? EXP2(sacc[j][r] * es) : 0.f;
          }
        } else {
#pragma unroll
          for (int j = 0; j < 4; j++)
#pragma unroll
            for (int r = 0; r < 4; r++) pm[j][r] = EXP2(sacc[j][r] * es);
        }
#pragma unroll
        for (int j = 0; j < 4; j++)
#pragma unroll
          for (int r = 0; r < 4; r++) lsum[r] += pm[j][r];

        // P: C-layout -> LDS (A-layout); wave-private strip, no block barrier
#pragma unroll
        for (int j = 0; j < 4; j++)
#pragma unroll
          for (int r = 0; r < 4; r++)
            Ps[(wv * 16 + qd * 4 + r) * PLD + j * 16 + cl] = f2bf(pm[j][r]);
        __asm__ volatile("s_waitcnt lgkmcnt(0)" ::: "memory");  // cross-lane

        // O += P V (n inner: dep distance 8)
#pragma unroll
        for (int kk = 0; kk < 2; kk++) {
          bf16x8 aP =
              *(const bf16x8*)&Ps[(wv * 16 + cl) * PLD + kk * 32 + qd * 8];
#pragma unroll
          for (int n = 0; n < 8; n++) {
            int row = n * 16 + cl;
            int ch = (kk * 4 + qd) ^ (row & 7);
            bf16x8 bV = *(const bf16x8*)&Vs[koff + row * 64 + ch * 8];
            oacc[n] = mfma16(aP, bV, oacc[n]);
          }
        }
      }

      VMC(0);  // stage(kt+1) drained (latency hidden under compute)
      BAR;
      cur ^= 1;
    }

    // reduce row sums across the 16-lane column group, write O
#pragma unroll
    for (int r = 0; r < 4; r++) {
#pragma unroll
      for (int off = 8; off >= 1; off >>= 1)
        lsum[r] += __shfl_xor(lsum[r], off, 64);
    }
#pragma unroll
    for (int r = 0; r < 4; r++) {
      float il = 1.0f / lsum[r];
      int row = row_min + qd * 4 + r;
#pragma unroll
      for (int n = 0; n < 8; n++)
        O[(size_t)row * HID + h * HD + n * 16 + cl] = f2bf(oacc[n][r] * il);
    }
  }
}

// ---------------- launch ----------------
extern "C" void kernel_launch(void* const* d_in, const int* in_sizes, int n_in,
                              void* d_out, int out_size, void* d_ws, size_t ws_size,
                              hipStream_t stream) {
  const float* hs = (const float*)d_in[0];
  const int* pos = (const int*)d_in[1];
  const float* Wq = (const float*)d_in[2];
  const float* Wk = (const float*)d_in[3];
  const float* Wv = (const float*)d_in[4];
  const float* Wo = (const float*)d_in[5];
  const float* qsc = (const float*)d_in[6];
  const float* ksc = (const float*)d_in[7];
  float* out = (float*)d_out;
  char* ws = (char*)d_ws;
  const size_t MB = 1u << 20;

  u16* hs_b  = (u16*)(ws + 0 * MB);   // 16 MB; reused for attention output
  u16* wq_b  = (u16*)(ws + 16 * MB);  // 32 MB  } wq|wk|wv contiguous ->
  u16* wk_b  = (u16*)(ws + 48 * MB);  // 8 MB   }   B[6144][4096]
  u16* wv_b  = (u16*)(ws + 56 * MB);  // 8 MB   }
  u16* qkv_b = (u16*)(ws + 64 * MB);  // 24 MB: [2048][6144] = Q|K|V
  u16* vt_b  = (u16*)(ws + 88 * MB);  // 4 MB: V^T [1024][2048]
  u16* wo_b  = (u16*)(ws + 92 * MB);  // 32 MB
  u16* o_b   = hs_b;                  // hs dead after qkv gemm

  static bool attr_set = false;
  if (!attr_set) {
    hipFuncSetAttribute(reinterpret_cast<const void*>(&gemm4p<3>),
                        hipFuncAttributeMaxDynamicSharedMemorySize, 114688);
    hipFuncSetAttribute(reinterpret_cast<const void*>(&gemm4p<2>),
                        hipFuncAttributeMaxDynamicSharedMemorySize, 98304);
    hipFuncSetAttribute(reinterpret_cast<const void*>(&flash_attn),
                        hipFuncAttributeMaxDynamicSharedMemorySize, 82944);
    attr_set = true;
  }

  conv_all<<<49152, 256, 0, stream>>>(hs, Wq, Wk, Wv, Wo,
                                      hs_b, wq_b, wk_b, wv_b, wo_b);

  // fused QKV projection: [2048][4096] x [6144][4096]^T -> [2048][6144]
  // BN=192 -> grid 8 x 32 = 256 blocks = 1/CU exactly
  gemm4p<3><<<dim3(8 * (QS / 192)), 512, 114688, stream>>>(
      hs_b, wq_b, qkv_b, nullptr, QS, HID);

  rope_l2norm<<<S_LEN * NH / 4, 256, 0, stream>>>(qkv_b, pos, qsc, NH - 1, 5, QS);
  rope_l2norm<<<S_LEN * NKV / 4, 256, 0, stream>>>(qkv_b + 4096, pos, ksc, NKV - 1, 3, QS);
  transpose_v<<<dim3(S_LEN / 64, (NKV * HD) / 64), 256, 0, stream>>>(qkv_b + 5120, vt_b);

  flash_attn<<<dim3(8, NH), 512, 82944, stream>>>(qkv_b, vt_b, o_b);

  // output projection: [2048][4096] x [4096][4096]^T -> f32 out
  // BN=128 -> grid 8 x 32 = 256 blocks = 1/CU exactly
  gemm4p<2><<<dim3(8 * (HID / 128)), 512, 98304, stream>>>(
      o_b, wo_b, nullptr, out, HID, HID);
}